// Round 1
// baseline (2034.672 us; speedup 1.0000x reference)
//
#include <hip/hip_runtime.h>
#include <math.h>

#define N_NODES 50000
#define E_EDGES 800000
#define D_DIM   64
#define H_HEADS 8
#define DH_DIM  8
#define EPS_BN  1e-5f

// ---------------------------------------------------------------------------
// K1: fused QKV GEMM. wave-per-row, lane j owns output column j.
//   Q[i,j] = sum_c h[i,c] * Wq[c,j] + bq[j]   (W row-major [64][64])
// ---------------------------------------------------------------------------
__global__ __launch_bounds__(256) void qkv_kernel(
    const float* __restrict__ h,
    const float* __restrict__ Wq, const float* __restrict__ bq,
    const float* __restrict__ Wk, const float* __restrict__ bk,
    const float* __restrict__ Wv, const float* __restrict__ bv,
    float* __restrict__ Q, float* __restrict__ K, float* __restrict__ V)
{
    const int lane = threadIdx.x & 63;
    const int wave = threadIdx.x >> 6;
    const int rowStep = gridDim.x * 4;
    for (int row = blockIdx.x * 4 + wave; row < N_NODES; row += rowStep) {
        const float hl = h[(size_t)row * 64 + lane];
        float q = bq[lane], k = bk[lane], v = bv[lane];
        #pragma unroll 16
        for (int c = 0; c < 64; ++c) {
            const float hc = __shfl(hl, c, 64);
            q = fmaf(hc, Wq[c * 64 + lane], q);
            k = fmaf(hc, Wk[c * 64 + lane], k);
            v = fmaf(hc, Wv[c * 64 + lane], v);
        }
        Q[(size_t)row * 64 + lane] = q;
        K[(size_t)row * 64 + lane] = k;
        V[(size_t)row * 64 + lane] = v;
    }
}

// ---------------------------------------------------------------------------
// K2: per-edge score + scatter. 8 lanes per edge (one lane per head).
// ---------------------------------------------------------------------------
__global__ __launch_bounds__(256) void edge_kernel(
    const int* __restrict__ src, const int* __restrict__ dst,
    const float* __restrict__ Q, const float* __restrict__ K,
    const float* __restrict__ V,
    float* __restrict__ wV, float* __restrict__ z)
{
    const long long gid = (long long)blockIdx.x * blockDim.x + threadIdx.x;
    const int e  = (int)(gid >> 3);
    const int hh = (int)(gid & 7);
    if (e >= E_EDGES) return;
    const int s = src[e];
    const int d = dst[e];

    const float4* kp = (const float4*)(K + (size_t)s * 64 + hh * 8);
    const float4* qp = (const float4*)(Q + (size_t)d * 64 + hh * 8);
    const float4 k0 = kp[0], k1 = kp[1];
    const float4 q0 = qp[0], q1 = qp[1];
    float sc = k0.x * q0.x + k0.y * q0.y + k0.z * q0.z + k0.w * q0.w
             + k1.x * q1.x + k1.y * q1.y + k1.z * q1.z + k1.w * q1.w;
    sc *= 0.35355339059327373f;              // 1/sqrt(8)
    sc = fminf(5.0f, fmaxf(-5.0f, sc));
    const float p = __expf(sc);

    const float4* vp = (const float4*)(V + (size_t)s * 64 + hh * 8);
    const float4 v0 = vp[0], v1 = vp[1];
    float* wp = wV + (size_t)d * 64 + hh * 8;
    unsafeAtomicAdd(wp + 0, p * v0.x);
    unsafeAtomicAdd(wp + 1, p * v0.y);
    unsafeAtomicAdd(wp + 2, p * v0.z);
    unsafeAtomicAdd(wp + 3, p * v0.w);
    unsafeAtomicAdd(wp + 4, p * v1.x);
    unsafeAtomicAdd(wp + 5, p * v1.y);
    unsafeAtomicAdd(wp + 6, p * v1.z);
    unsafeAtomicAdd(wp + 7, p * v1.w);
    unsafeAtomicAdd(z + (size_t)d * 8 + hh, p);
}

// ---------------------------------------------------------------------------
// K3: x = h + attn (normalize wV by z), x overwrites wV buffer; BN1 partials.
// ---------------------------------------------------------------------------
__global__ __launch_bounds__(256) void attn_bn1_kernel(
    const float* __restrict__ h, float* __restrict__ wVx,
    const float* __restrict__ z,
    float* __restrict__ s1, float* __restrict__ sq1)
{
    __shared__ float ls[256];
    __shared__ float lq[256];
    float sum = 0.0f, sumsq = 0.0f;
    const long long total = (long long)N_NODES * 64;
    const long long stride = (long long)gridDim.x * blockDim.x;  // multiple of 64
    for (long long idx = (long long)blockIdx.x * blockDim.x + threadIdx.x;
         idx < total; idx += stride) {
        const int node = (int)(idx >> 6);
        const int hh   = (int)((idx & 63) >> 3);
        const float zv = z[(size_t)node * 8 + hh];
        const float wv = wVx[idx];
        const float attn = (zv == 0.0f) ? 0.0f : wv / zv;
        const float x = h[idx] + attn;
        wVx[idx] = x;
        sum += x;
        sumsq += x * x;
    }
    ls[threadIdx.x] = sum;
    lq[threadIdx.x] = sumsq;
    __syncthreads();
    if (threadIdx.x < 64) {
        const float s = ls[threadIdx.x] + ls[threadIdx.x + 64] +
                        ls[threadIdx.x + 128] + ls[threadIdx.x + 192];
        const float q = lq[threadIdx.x] + lq[threadIdx.x + 64] +
                        lq[threadIdx.x + 128] + lq[threadIdx.x + 192];
        atomicAdd(s1 + threadIdx.x, s);
        atomicAdd(sq1 + threadIdx.x, q);
    }
}

// ---------------------------------------------------------------------------
// K4: finalize BN stats (mean, rstd). One block, 64 threads.
// ---------------------------------------------------------------------------
__global__ void stats_fin_kernel(const float* __restrict__ s,
                                 const float* __restrict__ sq,
                                 float* __restrict__ m, float* __restrict__ rs)
{
    const int c = threadIdx.x;
    const float mean = s[c] * (1.0f / N_NODES);
    const float var  = sq[c] * (1.0f / N_NODES) - mean * mean;
    m[c]  = mean;
    rs[c] = rsqrtf(var + EPS_BN);
}

// ---------------------------------------------------------------------------
// K5: fused BN1-apply + FFN (64->128 relu ->64) + residual; BN2 partials.
// wave-per-row; lane j owns column j.
// ---------------------------------------------------------------------------
__global__ __launch_bounds__(256) void ffn_kernel(
    const float* __restrict__ x,
    const float* __restrict__ m1, const float* __restrict__ rs1,
    const float* __restrict__ g1, const float* __restrict__ b1,
    const float* __restrict__ W1, const float* __restrict__ bb1,
    const float* __restrict__ W2, const float* __restrict__ bb2,
    float* __restrict__ y, float* __restrict__ s2, float* __restrict__ sq2)
{
    const int lane = threadIdx.x & 63;
    const int wave = threadIdx.x >> 6;
    const float a1 = rs1[lane] * g1[lane];
    const float c1 = b1[lane] - m1[lane] * a1;
    const float bb1a = bb1[lane];
    const float bb1b = bb1[64 + lane];
    const float bb2l = bb2[lane];
    float sum = 0.0f, sumsq = 0.0f;
    const int rowStep = gridDim.x * 4;
    for (int row = blockIdx.x * 4 + wave; row < N_NODES; row += rowStep) {
        const float xl = x[(size_t)row * 64 + lane];
        const float h1 = fmaf(xl, a1, c1);
        float ta = bb1a, tb = bb1b;
        #pragma unroll 16
        for (int c = 0; c < 64; ++c) {
            const float hc = __shfl(h1, c, 64);
            ta = fmaf(hc, W1[c * 128 + lane], ta);
            tb = fmaf(hc, W1[c * 128 + 64 + lane], tb);
        }
        ta = fmaxf(ta, 0.0f);
        tb = fmaxf(tb, 0.0f);
        float f = bb2l;
        #pragma unroll 16
        for (int j = 0; j < 64; ++j) {
            const float t1 = __shfl(ta, j, 64);
            const float t2 = __shfl(tb, j, 64);
            f = fmaf(t1, W2[j * 64 + lane], f);
            f = fmaf(t2, W2[(64 + j) * 64 + lane], f);
        }
        const float yv = h1 + f;
        y[(size_t)row * 64 + lane] = yv;
        sum += yv;
        sumsq += yv * yv;
    }
    __shared__ float ls[256];
    __shared__ float lq[256];
    ls[threadIdx.x] = sum;
    lq[threadIdx.x] = sumsq;
    __syncthreads();
    if (threadIdx.x < 64) {
        const float s = ls[threadIdx.x] + ls[threadIdx.x + 64] +
                        ls[threadIdx.x + 128] + ls[threadIdx.x + 192];
        const float q = lq[threadIdx.x] + lq[threadIdx.x + 64] +
                        lq[threadIdx.x + 128] + lq[threadIdx.x + 192];
        atomicAdd(s2 + threadIdx.x, s);
        atomicAdd(sq2 + threadIdx.x, q);
    }
}

// ---------------------------------------------------------------------------
// K6: apply BN2 in place on y (= d_out).
// ---------------------------------------------------------------------------
__global__ __launch_bounds__(256) void bn2_apply_kernel(
    float* __restrict__ y,
    const float* __restrict__ m2, const float* __restrict__ rs2,
    const float* __restrict__ g2, const float* __restrict__ b2)
{
    const long long total = (long long)N_NODES * 64;
    const long long stride = (long long)gridDim.x * blockDim.x;
    for (long long idx = (long long)blockIdx.x * blockDim.x + threadIdx.x;
         idx < total; idx += stride) {
        const int c = (int)(idx & 63);
        y[idx] = (y[idx] - m2[c]) * rs2[c] * g2[c] + b2[c];
    }
}

extern "C" void kernel_launch(void* const* d_in, const int* in_sizes, int n_in,
                              void* d_out, int out_size, void* d_ws, size_t ws_size,
                              hipStream_t stream)
{
    const float* h   = (const float*)d_in[0];
    const int*   src = (const int*)d_in[1];
    const int*   dst = (const int*)d_in[2];
    const float* Wq  = (const float*)d_in[3];
    const float* bq  = (const float*)d_in[4];
    const float* Wk  = (const float*)d_in[5];
    const float* bk  = (const float*)d_in[6];
    const float* Wv  = (const float*)d_in[7];
    const float* bv  = (const float*)d_in[8];
    const float* g1  = (const float*)d_in[9];
    const float* b1  = (const float*)d_in[10];
    const float* W1  = (const float*)d_in[11];
    const float* bb1 = (const float*)d_in[12];
    const float* W2  = (const float*)d_in[13];
    const float* bb2 = (const float*)d_in[14];
    const float* g2  = (const float*)d_in[15];
    const float* b2  = (const float*)d_in[16];
    float* out = (float*)d_out;

    float* ws = (float*)d_ws;
    const size_t ND = (size_t)N_NODES * 64;
    float* Q    = ws;
    float* K    = ws + ND;
    float* V    = ws + 2 * ND;
    float* wVx  = ws + 3 * ND;                       // wV, then x in-place
    float* z    = ws + 4 * ND;                       // [N,H]
    float* st   = ws + 4 * ND + (size_t)N_NODES * 8; // stats block
    float* s1 = st,        *sq1 = st + 64,  *m1 = st + 128, *rs1 = st + 192;
    float* s2 = st + 256,  *sq2 = st + 320, *m2 = st + 384, *rs2 = st + 448;

    // zero wV, z, stats (contiguous)
    const size_t zeroBytes = (ND + (size_t)N_NODES * 8 + 512) * sizeof(float);
    hipMemsetAsync(wVx, 0, zeroBytes, stream);

    qkv_kernel<<<12500, 256, 0, stream>>>(h, Wq, bq, Wk, bk, Wv, bv, Q, K, V);
    edge_kernel<<<(E_EDGES * 8) / 256, 256, 0, stream>>>(src, dst, Q, K, V, wVx, z);
    attn_bn1_kernel<<<1024, 256, 0, stream>>>(h, wVx, z, s1, sq1);
    stats_fin_kernel<<<1, 64, 0, stream>>>(s1, sq1, m1, rs1);
    ffn_kernel<<<12500, 256, 0, stream>>>(wVx, m1, rs1, g1, b1, W1, bb1, W2, bb2,
                                          out, s2, sq2);
    stats_fin_kernel<<<1, 64, 0, stream>>>(s2, sq2, m2, rs2);
    bn2_apply_kernel<<<2048, 256, 0, stream>>>(out, m2, rs2, g2, b2);
}

// Round 2
// 1556.221 us; speedup vs baseline: 1.3074x; 1.3074x over previous
//
#include <hip/hip_runtime.h>
#include <math.h>

#define N_NODES 50000
#define E_EDGES 800000
#define D_DIM   64
#define H_HEADS 8
#define DH_DIM  8
#define EPS_BN  1e-5f

// ---------------------------------------------------------------------------
// K1: fused QKV GEMM. wave-per-row, lane j owns output column j.
// ---------------------------------------------------------------------------
__global__ __launch_bounds__(256) void qkv_kernel(
    const float* __restrict__ h,
    const float* __restrict__ Wq, const float* __restrict__ bq,
    const float* __restrict__ Wk, const float* __restrict__ bk,
    const float* __restrict__ Wv, const float* __restrict__ bv,
    float* __restrict__ Q, float* __restrict__ K, float* __restrict__ V)
{
    const int lane = threadIdx.x & 63;
    const int wave = threadIdx.x >> 6;
    const int rowStep = gridDim.x * 4;
    for (int row = blockIdx.x * 4 + wave; row < N_NODES; row += rowStep) {
        const float hl = h[(size_t)row * 64 + lane];
        float q = bq[lane], k = bk[lane], v = bv[lane];
        #pragma unroll 16
        for (int c = 0; c < 64; ++c) {
            const float hc = __shfl(hl, c, 64);
            q = fmaf(hc, Wq[c * 64 + lane], q);
            k = fmaf(hc, Wk[c * 64 + lane], k);
            v = fmaf(hc, Wv[c * 64 + lane], v);
        }
        Q[(size_t)row * 64 + lane] = q;
        K[(size_t)row * 64 + lane] = k;
        V[(size_t)row * 64 + lane] = v;
    }
}

// ---------------------------------------------------------------------------
// K2a: histogram of dst. count[] pre-zeroed by memset.
// ---------------------------------------------------------------------------
__global__ __launch_bounds__(256) void hist_kernel(
    const int* __restrict__ dst, int* __restrict__ count)
{
    const int e = blockIdx.x * 256 + threadIdx.x;
    if (e < E_EDGES) atomicAdd(&count[dst[e]], 1);
}

// ---------------------------------------------------------------------------
// K2b: exclusive prefix scan over count[0..N) -> rowStart[0..N] and cursor.
// single block, 1024 threads, chunk-serial + LDS Hillis-Steele.
// ---------------------------------------------------------------------------
#define SCAN_CHUNK 49   // ceil(50000/1024)
__global__ __launch_bounds__(1024) void scan_kernel(
    const int* __restrict__ count,
    int* __restrict__ rowStart, int* __restrict__ cursor)
{
    __shared__ int ls[1024];
    const int t = threadIdx.x;
    const int begin = t * SCAN_CHUNK;
    const int endc = min(begin + SCAN_CHUNK, N_NODES);
    int s = 0;
    for (int i = begin; i < endc; ++i) s += count[i];
    ls[t] = s;
    __syncthreads();
    #pragma unroll
    for (int off = 1; off < 1024; off <<= 1) {
        int v = (t >= off) ? ls[t - off] : 0;
        __syncthreads();
        ls[t] += v;
        __syncthreads();
    }
    int prefix = (t == 0) ? 0 : ls[t - 1];
    for (int i = begin; i < endc; ++i) {
        rowStart[i] = prefix;
        cursor[i]   = prefix;
        prefix += count[i];
    }
    if (t == 1023) rowStart[N_NODES] = ls[1023];
}

// ---------------------------------------------------------------------------
// K2c: scatter src into dst-sorted order.
// ---------------------------------------------------------------------------
__global__ __launch_bounds__(256) void scatter_kernel(
    const int* __restrict__ src, const int* __restrict__ dst,
    int* __restrict__ cursor, int* __restrict__ srcSorted)
{
    const int e = blockIdx.x * 256 + threadIdx.x;
    if (e < E_EDGES) {
        const int pos = atomicAdd(&cursor[dst[e]], 1);
        srcSorted[pos] = src[e];
    }
}

// ---------------------------------------------------------------------------
// K3: gather-based edge aggregation, fused with attn-normalize + residual +
// BN1 partial sums. One wave per dst node; 8 lanes per edge (lane&7 = head).
// NOTE: x may alias Q (Q[n] is consumed before x[n] is written, same wave).
// ---------------------------------------------------------------------------
__global__ __launch_bounds__(256) void gather_edge_kernel(
    const float* __restrict__ h,
    const float* __restrict__ Q, const float* __restrict__ K,
    const float* __restrict__ V,
    const int* __restrict__ rowStart, const int* __restrict__ srcSorted,
    float* __restrict__ x, float* __restrict__ s1, float* __restrict__ sq1)
{
    const int lane = threadIdx.x & 63;
    const int wave = threadIdx.x >> 6;
    const int hh = lane & 7;   // head
    const int el = lane >> 3;  // edge slot within wave (0..7)
    float bsum[8], bsq[8];
    #pragma unroll
    for (int j = 0; j < 8; ++j) { bsum[j] = 0.0f; bsq[j] = 0.0f; }

    const int nodeStep = gridDim.x * 4;
    for (int n = blockIdx.x * 4 + wave; n < N_NODES; n += nodeStep) {
        const int start = rowStart[n];
        const int end   = rowStart[n + 1];
        const size_t qb = (size_t)n * 64 + hh * 8;
        const float4 q0 = *(const float4*)(Q + qb);
        const float4 q1 = *(const float4*)(Q + qb + 4);
        float a0=0,a1=0,a2=0,a3=0,a4=0,a5=0,a6=0,a7=0,zacc=0;
        for (int e = start + el; e < end; e += 8) {
            const int s = srcSorted[e];
            const size_t kb = (size_t)s * 64 + hh * 8;
            const float4 k0 = *(const float4*)(K + kb);
            const float4 k1 = *(const float4*)(K + kb + 4);
            float sc = k0.x*q0.x + k0.y*q0.y + k0.z*q0.z + k0.w*q0.w
                     + k1.x*q1.x + k1.y*q1.y + k1.z*q1.z + k1.w*q1.w;
            sc *= 0.35355339059327373f;   // 1/sqrt(8)
            sc = fminf(5.0f, fmaxf(-5.0f, sc));
            const float p = __expf(sc);
            const float4 v0 = *(const float4*)(V + kb);
            const float4 v1 = *(const float4*)(V + kb + 4);
            a0 = fmaf(p, v0.x, a0); a1 = fmaf(p, v0.y, a1);
            a2 = fmaf(p, v0.z, a2); a3 = fmaf(p, v0.w, a3);
            a4 = fmaf(p, v1.x, a4); a5 = fmaf(p, v1.y, a5);
            a6 = fmaf(p, v1.z, a6); a7 = fmaf(p, v1.w, a7);
            zacc += p;
        }
        // reduce across the 8 edge-slots (lanes differing in bits 3..5)
        #pragma unroll
        for (int m = 8; m < 64; m <<= 1) {
            a0 += __shfl_xor(a0, m, 64); a1 += __shfl_xor(a1, m, 64);
            a2 += __shfl_xor(a2, m, 64); a3 += __shfl_xor(a3, m, 64);
            a4 += __shfl_xor(a4, m, 64); a5 += __shfl_xor(a5, m, 64);
            a6 += __shfl_xor(a6, m, 64); a7 += __shfl_xor(a7, m, 64);
            zacc += __shfl_xor(zacc, m, 64);
        }
        if (el == 0) {
            const float inv = (zacc == 0.0f) ? 0.0f : 1.0f / zacc;
            const float4 h0 = *(const float4*)(h + qb);
            const float4 h1 = *(const float4*)(h + qb + 4);
            float xv[8];
            xv[0] = fmaf(a0, inv, h0.x); xv[1] = fmaf(a1, inv, h0.y);
            xv[2] = fmaf(a2, inv, h0.z); xv[3] = fmaf(a3, inv, h0.w);
            xv[4] = fmaf(a4, inv, h1.x); xv[5] = fmaf(a5, inv, h1.y);
            xv[6] = fmaf(a6, inv, h1.z); xv[7] = fmaf(a7, inv, h1.w);
            *(float4*)(x + qb)     = make_float4(xv[0], xv[1], xv[2], xv[3]);
            *(float4*)(x + qb + 4) = make_float4(xv[4], xv[5], xv[6], xv[7]);
            #pragma unroll
            for (int j = 0; j < 8; ++j) {
                bsum[j] += xv[j];
                bsq[j]  += xv[j] * xv[j];
            }
        }
    }
    // block-level BN1 partial reduction: slot = wave*64 + hh*8 + j
    __shared__ float lsm[256];
    __shared__ float lsq[256];
    if (el == 0) {
        #pragma unroll
        for (int j = 0; j < 8; ++j) {
            lsm[wave * 64 + hh * 8 + j] = bsum[j];
            lsq[wave * 64 + hh * 8 + j] = bsq[j];
        }
    }
    __syncthreads();
    if (threadIdx.x < 64) {
        const int t = threadIdx.x;
        const float s = lsm[t] + lsm[t + 64] + lsm[t + 128] + lsm[t + 192];
        const float q = lsq[t] + lsq[t + 64] + lsq[t + 128] + lsq[t + 192];
        atomicAdd(s1 + t, s);
        atomicAdd(sq1 + t, q);
    }
}

// ---------------------------------------------------------------------------
// K4: finalize BN stats (mean, rstd). One block, 64 threads.
// ---------------------------------------------------------------------------
__global__ void stats_fin_kernel(const float* __restrict__ s,
                                 const float* __restrict__ sq,
                                 float* __restrict__ m, float* __restrict__ rs)
{
    const int c = threadIdx.x;
    const float mean = s[c] * (1.0f / N_NODES);
    const float var  = sq[c] * (1.0f / N_NODES) - mean * mean;
    m[c]  = mean;
    rs[c] = rsqrtf(var + EPS_BN);
}

// ---------------------------------------------------------------------------
// K5: fused BN1-apply + FFN (64->128 relu ->64) + residual; BN2 partials.
// ---------------------------------------------------------------------------
__global__ __launch_bounds__(256) void ffn_kernel(
    const float* __restrict__ x,
    const float* __restrict__ m1, const float* __restrict__ rs1,
    const float* __restrict__ g1, const float* __restrict__ b1,
    const float* __restrict__ W1, const float* __restrict__ bb1,
    const float* __restrict__ W2, const float* __restrict__ bb2,
    float* __restrict__ y, float* __restrict__ s2, float* __restrict__ sq2)
{
    const int lane = threadIdx.x & 63;
    const int wave = threadIdx.x >> 6;
    const float a1 = rs1[lane] * g1[lane];
    const float c1 = b1[lane] - m1[lane] * a1;
    const float bb1a = bb1[lane];
    const float bb1b = bb1[64 + lane];
    const float bb2l = bb2[lane];
    float sum = 0.0f, sumsq = 0.0f;
    const int rowStep = gridDim.x * 4;
    for (int row = blockIdx.x * 4 + wave; row < N_NODES; row += rowStep) {
        const float xl = x[(size_t)row * 64 + lane];
        const float h1 = fmaf(xl, a1, c1);
        float ta = bb1a, tb = bb1b;
        #pragma unroll 16
        for (int c = 0; c < 64; ++c) {
            const float hc = __shfl(h1, c, 64);
            ta = fmaf(hc, W1[c * 128 + lane], ta);
            tb = fmaf(hc, W1[c * 128 + 64 + lane], tb);
        }
        ta = fmaxf(ta, 0.0f);
        tb = fmaxf(tb, 0.0f);
        float f = bb2l;
        #pragma unroll 16
        for (int j = 0; j < 64; ++j) {
            const float t1 = __shfl(ta, j, 64);
            const float t2 = __shfl(tb, j, 64);
            f = fmaf(t1, W2[j * 64 + lane], f);
            f = fmaf(t2, W2[(64 + j) * 64 + lane], f);
        }
        const float yv = h1 + f;
        y[(size_t)row * 64 + lane] = yv;
        sum += yv;
        sumsq += yv * yv;
    }
    __shared__ float ls[256];
    __shared__ float lq[256];
    ls[threadIdx.x] = sum;
    lq[threadIdx.x] = sumsq;
    __syncthreads();
    if (threadIdx.x < 64) {
        const float s = ls[threadIdx.x] + ls[threadIdx.x + 64] +
                        ls[threadIdx.x + 128] + ls[threadIdx.x + 192];
        const float q = lq[threadIdx.x] + lq[threadIdx.x + 64] +
                        lq[threadIdx.x + 128] + lq[threadIdx.x + 192];
        atomicAdd(s2 + threadIdx.x, s);
        atomicAdd(sq2 + threadIdx.x, q);
    }
}

// ---------------------------------------------------------------------------
// K6: apply BN2 in place on y (= d_out).
// ---------------------------------------------------------------------------
__global__ __launch_bounds__(256) void bn2_apply_kernel(
    float* __restrict__ y,
    const float* __restrict__ m2, const float* __restrict__ rs2,
    const float* __restrict__ g2, const float* __restrict__ b2)
{
    const long long total = (long long)N_NODES * 64;
    const long long stride = (long long)gridDim.x * blockDim.x;
    for (long long idx = (long long)blockIdx.x * blockDim.x + threadIdx.x;
         idx < total; idx += stride) {
        const int c = (int)(idx & 63);
        y[idx] = (y[idx] - m2[c]) * rs2[c] * g2[c] + b2[c];
    }
}

extern "C" void kernel_launch(void* const* d_in, const int* in_sizes, int n_in,
                              void* d_out, int out_size, void* d_ws, size_t ws_size,
                              hipStream_t stream)
{
    const float* h   = (const float*)d_in[0];
    const int*   src = (const int*)d_in[1];
    const int*   dst = (const int*)d_in[2];
    const float* Wq  = (const float*)d_in[3];
    const float* bq  = (const float*)d_in[4];
    const float* Wk  = (const float*)d_in[5];
    const float* bk  = (const float*)d_in[6];
    const float* Wv  = (const float*)d_in[7];
    const float* bv  = (const float*)d_in[8];
    const float* g1  = (const float*)d_in[9];
    const float* b1  = (const float*)d_in[10];
    const float* W1  = (const float*)d_in[11];
    const float* bb1 = (const float*)d_in[12];
    const float* W2  = (const float*)d_in[13];
    const float* bb2 = (const float*)d_in[14];
    const float* g2  = (const float*)d_in[15];
    const float* b2  = (const float*)d_in[16];
    float* out = (float*)d_out;

    float* ws = (float*)d_ws;
    const size_t ND = (size_t)N_NODES * 64;
    float* Q = ws;            // later reused as x (safe: Q[n] read before x[n] write)
    float* K = ws + ND;
    float* V = ws + 2 * ND;
    float* x = Q;
    int* srcSorted = (int*)(ws + 3 * ND);          // E
    int* count     = srcSorted + E_EDGES;          // N   (zeroed)
    float* st      = (float*)(count + N_NODES);    // 512 floats (zeroed)
    int* rowStart  = (int*)(st + 512);             // N+1
    int* cursor    = rowStart + N_NODES + 1;       // N
    float* s1 = st,       *sq1 = st + 64,  *m1 = st + 128, *rs1 = st + 192;
    float* s2 = st + 256, *sq2 = st + 320, *m2 = st + 384, *rs2 = st + 448;

    // zero count + stats (contiguous)
    hipMemsetAsync(count, 0, (N_NODES + 512) * sizeof(int), stream);

    qkv_kernel<<<12500, 256, 0, stream>>>(h, Wq, bq, Wk, bk, Wv, bv, Q, K, V);
    hist_kernel<<<3125, 256, 0, stream>>>(dst, count);
    scan_kernel<<<1, 1024, 0, stream>>>(count, rowStart, cursor);
    scatter_kernel<<<3125, 256, 0, stream>>>(src, dst, cursor, srcSorted);
    gather_edge_kernel<<<1024, 256, 0, stream>>>(h, Q, K, V, rowStart, srcSorted,
                                                 x, s1, sq1);
    stats_fin_kernel<<<1, 64, 0, stream>>>(s1, sq1, m1, rs1);
    ffn_kernel<<<12500, 256, 0, stream>>>(x, m1, rs1, g1, b1, W1, bb1, W2, bb2,
                                          out, s2, sq2);
    stats_fin_kernel<<<1, 64, 0, stream>>>(s2, sq2, m2, rs2);
    bn2_apply_kernel<<<2048, 256, 0, stream>>>(out, m2, rs2, g2, b2);
}

// Round 3
// 501.217 us; speedup vs baseline: 4.0595x; 3.1049x over previous
//
#include <hip/hip_runtime.h>
#include <math.h>

#define N_NODES 50000
#define E_EDGES 800000
#define EPS_BN  1e-5f

// ---------------------------------------------------------------------------
// K1: fused QKV GEMM, register-tiled. Block = 256 thr, tile = 64 rows.
// thread (ty,tx): rows ty*4..+3, cols tx*4..+3 of each of Q/K/V.
// ---------------------------------------------------------------------------
__global__ __launch_bounds__(256) void qkv_kernel(
    const float* __restrict__ h,
    const float* __restrict__ Wq, const float* __restrict__ bq,
    const float* __restrict__ Wk, const float* __restrict__ bk,
    const float* __restrict__ Wv, const float* __restrict__ bv,
    float* __restrict__ Q, float* __restrict__ K, float* __restrict__ V)
{
    __shared__ float xs[64][68];            // padded: stride 68 (16B-aligned rows)
    const int t  = threadIdx.x;
    const int tx = t & 15;
    const int ty = t >> 4;
    const int row0 = blockIdx.x * 64;

    // stage x tile (64x64), coalesced float4
    #pragma unroll
    for (int k = 0; k < 4; ++k) {
        const int i  = t + k * 256;
        const int r  = i >> 4;
        const int c4 = (i & 15) * 4;
        float4 v = make_float4(0.f, 0.f, 0.f, 0.f);
        if (row0 + r < N_NODES)
            v = *(const float4*)(h + (size_t)(row0 + r) * 64 + c4);
        *(float4*)(&xs[r][c4]) = v;
    }
    __syncthreads();

    const int c0 = tx * 4;
    float4 aq[4], ak[4], av[4];
    const float4 bq4 = *(const float4*)(bq + c0);
    const float4 bk4 = *(const float4*)(bk + c0);
    const float4 bv4 = *(const float4*)(bv + c0);
    #pragma unroll
    for (int i = 0; i < 4; ++i) { aq[i] = bq4; ak[i] = bk4; av[i] = bv4; }

    #pragma unroll 4
    for (int c = 0; c < 64; ++c) {
        const float4 wq = *(const float4*)(Wq + c * 64 + c0);
        const float4 wk = *(const float4*)(Wk + c * 64 + c0);
        const float4 wv = *(const float4*)(Wv + c * 64 + c0);
        #pragma unroll
        for (int i = 0; i < 4; ++i) {
            const float xv = xs[ty * 4 + i][c];
            aq[i].x = fmaf(xv, wq.x, aq[i].x); aq[i].y = fmaf(xv, wq.y, aq[i].y);
            aq[i].z = fmaf(xv, wq.z, aq[i].z); aq[i].w = fmaf(xv, wq.w, aq[i].w);
            ak[i].x = fmaf(xv, wk.x, ak[i].x); ak[i].y = fmaf(xv, wk.y, ak[i].y);
            ak[i].z = fmaf(xv, wk.z, ak[i].z); ak[i].w = fmaf(xv, wk.w, ak[i].w);
            av[i].x = fmaf(xv, wv.x, av[i].x); av[i].y = fmaf(xv, wv.y, av[i].y);
            av[i].z = fmaf(xv, wv.z, av[i].z); av[i].w = fmaf(xv, wv.w, av[i].w);
        }
    }
    #pragma unroll
    for (int i = 0; i < 4; ++i) {
        const int row = row0 + ty * 4 + i;
        if (row < N_NODES) {
            *(float4*)(Q + (size_t)row * 64 + c0) = aq[i];
            *(float4*)(K + (size_t)row * 64 + c0) = ak[i];
            *(float4*)(V + (size_t)row * 64 + c0) = av[i];
        }
    }
}

// ---------------------------------------------------------------------------
// K2a: histogram of dst.
// ---------------------------------------------------------------------------
__global__ __launch_bounds__(256) void hist_kernel(
    const int* __restrict__ dst, int* __restrict__ count)
{
    const int e = blockIdx.x * 256 + threadIdx.x;
    if (e < E_EDGES) atomicAdd(&count[dst[e]], 1);
}

// ---------------------------------------------------------------------------
// K2b: exclusive prefix scan -> rowStart[0..N], cursor.
// ---------------------------------------------------------------------------
#define SCAN_CHUNK 49
__global__ __launch_bounds__(1024) void scan_kernel(
    const int* __restrict__ count,
    int* __restrict__ rowStart, int* __restrict__ cursor)
{
    __shared__ int ls[1024];
    const int t = threadIdx.x;
    const int begin = t * SCAN_CHUNK;
    const int endc = min(begin + SCAN_CHUNK, N_NODES);
    int s = 0;
    for (int i = begin; i < endc; ++i) s += count[i];
    ls[t] = s;
    __syncthreads();
    #pragma unroll
    for (int off = 1; off < 1024; off <<= 1) {
        int v = (t >= off) ? ls[t - off] : 0;
        __syncthreads();
        ls[t] += v;
        __syncthreads();
    }
    int prefix = (t == 0) ? 0 : ls[t - 1];
    for (int i = begin; i < endc; ++i) {
        rowStart[i] = prefix;
        cursor[i]   = prefix;
        prefix += count[i];
    }
    if (t == 1023) rowStart[N_NODES] = ls[1023];
}

// ---------------------------------------------------------------------------
// K2c: scatter src into dst-sorted order.
// ---------------------------------------------------------------------------
__global__ __launch_bounds__(256) void scatter_kernel(
    const int* __restrict__ src, const int* __restrict__ dst,
    int* __restrict__ cursor, int* __restrict__ srcSorted)
{
    const int e = blockIdx.x * 256 + threadIdx.x;
    if (e < E_EDGES) {
        const int pos = atomicAdd(&cursor[dst[e]], 1);
        srcSorted[pos] = src[e];
    }
}

// ---------------------------------------------------------------------------
// K3: gather edge aggregation + attn-normalize + residual + BN1 partials.
// One wave per dst node; lane&7 = head, lane>>3 = edge slot.
// x may alias Q (Q[n] consumed before x[n] written by the same wave).
// ---------------------------------------------------------------------------
__global__ __launch_bounds__(256) void gather_edge_kernel(
    const float* __restrict__ h,
    const float* __restrict__ Q, const float* __restrict__ K,
    const float* __restrict__ V,
    const int* __restrict__ rowStart, const int* __restrict__ srcSorted,
    float* __restrict__ x, float* __restrict__ s1, float* __restrict__ sq1)
{
    const int lane = threadIdx.x & 63;
    const int wave = threadIdx.x >> 6;
    const int hh = lane & 7;
    const int el = lane >> 3;
    float bsum[8], bsq[8];
    #pragma unroll
    for (int j = 0; j < 8; ++j) { bsum[j] = 0.0f; bsq[j] = 0.0f; }

    const int nodeStep = gridDim.x * 4;
    for (int n = blockIdx.x * 4 + wave; n < N_NODES; n += nodeStep) {
        const int start = rowStart[n];
        const int end   = rowStart[n + 1];
        const size_t qb = (size_t)n * 64 + hh * 8;
        const float4 q0 = *(const float4*)(Q + qb);
        const float4 q1 = *(const float4*)(Q + qb + 4);
        float a0=0,a1=0,a2=0,a3=0,a4=0,a5=0,a6=0,a7=0,zacc=0;
        for (int e = start + el; e < end; e += 8) {
            const int s = srcSorted[e];
            const size_t kb = (size_t)s * 64 + hh * 8;
            const float4 k0 = *(const float4*)(K + kb);
            const float4 k1 = *(const float4*)(K + kb + 4);
            float sc = k0.x*q0.x + k0.y*q0.y + k0.z*q0.z + k0.w*q0.w
                     + k1.x*q1.x + k1.y*q1.y + k1.z*q1.z + k1.w*q1.w;
            sc *= 0.35355339059327373f;
            sc = fminf(5.0f, fmaxf(-5.0f, sc));
            const float p = __expf(sc);
            const float4 v0 = *(const float4*)(V + kb);
            const float4 v1 = *(const float4*)(V + kb + 4);
            a0 = fmaf(p, v0.x, a0); a1 = fmaf(p, v0.y, a1);
            a2 = fmaf(p, v0.z, a2); a3 = fmaf(p, v0.w, a3);
            a4 = fmaf(p, v1.x, a4); a5 = fmaf(p, v1.y, a5);
            a6 = fmaf(p, v1.z, a6); a7 = fmaf(p, v1.w, a7);
            zacc += p;
        }
        #pragma unroll
        for (int m = 8; m < 64; m <<= 1) {
            a0 += __shfl_xor(a0, m, 64); a1 += __shfl_xor(a1, m, 64);
            a2 += __shfl_xor(a2, m, 64); a3 += __shfl_xor(a3, m, 64);
            a4 += __shfl_xor(a4, m, 64); a5 += __shfl_xor(a5, m, 64);
            a6 += __shfl_xor(a6, m, 64); a7 += __shfl_xor(a7, m, 64);
            zacc += __shfl_xor(zacc, m, 64);
        }
        if (el == 0) {
            const float inv = (zacc == 0.0f) ? 0.0f : 1.0f / zacc;
            const float4 h0 = *(const float4*)(h + qb);
            const float4 h1 = *(const float4*)(h + qb + 4);
            float xv[8];
            xv[0] = fmaf(a0, inv, h0.x); xv[1] = fmaf(a1, inv, h0.y);
            xv[2] = fmaf(a2, inv, h0.z); xv[3] = fmaf(a3, inv, h0.w);
            xv[4] = fmaf(a4, inv, h1.x); xv[5] = fmaf(a5, inv, h1.y);
            xv[6] = fmaf(a6, inv, h1.z); xv[7] = fmaf(a7, inv, h1.w);
            *(float4*)(x + qb)     = make_float4(xv[0], xv[1], xv[2], xv[3]);
            *(float4*)(x + qb + 4) = make_float4(xv[4], xv[5], xv[6], xv[7]);
            #pragma unroll
            for (int j = 0; j < 8; ++j) {
                bsum[j] += xv[j];
                bsq[j]  += xv[j] * xv[j];
            }
        }
    }
    __shared__ float lsm[256];
    __shared__ float lsq[256];
    if (el == 0) {
        #pragma unroll
        for (int j = 0; j < 8; ++j) {
            lsm[wave * 64 + hh * 8 + j] = bsum[j];
            lsq[wave * 64 + hh * 8 + j] = bsq[j];
        }
    }
    __syncthreads();
    if (threadIdx.x < 64) {
        const int tt = threadIdx.x;
        const float s = lsm[tt] + lsm[tt + 64] + lsm[tt + 128] + lsm[tt + 192];
        const float q = lsq[tt] + lsq[tt + 64] + lsq[tt + 128] + lsq[tt + 192];
        atomicAdd(s1 + tt, s);
        atomicAdd(sq1 + tt, q);
    }
}

// ---------------------------------------------------------------------------
// K4: finalize BN stats.
// ---------------------------------------------------------------------------
__global__ void stats_fin_kernel(const float* __restrict__ s,
                                 const float* __restrict__ sq,
                                 float* __restrict__ m, float* __restrict__ rs)
{
    const int c = threadIdx.x;
    const float mean = s[c] * (1.0f / N_NODES);
    const float var  = sq[c] * (1.0f / N_NODES) - mean * mean;
    m[c]  = mean;
    rs[c] = rsqrtf(var + EPS_BN);
}

// ---------------------------------------------------------------------------
// K5: fused BN1-apply + FFN + residual + BN2 partials, register-tiled.
// Block = 256 thr, tile = 32 rows. Phase1: T=relu(h1@W1+bb1) (thread: 2 rows x
// 2x4 cols). Phase2: y=h1+T@W2+bb2 (thread: 2 rows x 4 cols).
// ---------------------------------------------------------------------------
__global__ __launch_bounds__(256) void ffn_kernel(
    const float* __restrict__ x,
    const float* __restrict__ m1, const float* __restrict__ rs1,
    const float* __restrict__ g1, const float* __restrict__ b1,
    const float* __restrict__ W1, const float* __restrict__ bb1,
    const float* __restrict__ W2, const float* __restrict__ bb2,
    float* __restrict__ y, float* __restrict__ s2, float* __restrict__ sq2)
{
    __shared__ float xs[32][68];     // h1 (BN1-applied), padded
    __shared__ float ts[32][132];    // hidden activations, padded
    __shared__ float reds[16][64];
    __shared__ float redq[16][64];

    const int t  = threadIdx.x;
    const int tx = t & 15;
    const int ty = t >> 4;
    const int row0 = blockIdx.x * 32;

    // stage + BN1: each thread loads 2 float4 groups, fixed channel group
    {
        const int c4 = (t & 15) * 4;
        const float4 mm = *(const float4*)(m1 + c4);
        const float4 rr = *(const float4*)(rs1 + c4);
        const float4 gg = *(const float4*)(g1 + c4);
        const float4 bb = *(const float4*)(b1 + c4);
        float4 A, C;
        A.x = rr.x * gg.x; C.x = bb.x - mm.x * A.x;
        A.y = rr.y * gg.y; C.y = bb.y - mm.y * A.y;
        A.z = rr.z * gg.z; C.z = bb.z - mm.z * A.z;
        A.w = rr.w * gg.w; C.w = bb.w - mm.w * A.w;
        #pragma unroll
        for (int k = 0; k < 2; ++k) {
            const int i = t + k * 256;
            const int r = i >> 4;
            float4 v = make_float4(0.f, 0.f, 0.f, 0.f);
            if (row0 + r < N_NODES) {
                const float4 xv = *(const float4*)(x + (size_t)(row0 + r) * 64 + c4);
                v.x = fmaf(xv.x, A.x, C.x);
                v.y = fmaf(xv.y, A.y, C.y);
                v.z = fmaf(xv.z, A.z, C.z);
                v.w = fmaf(xv.w, A.w, C.w);
            }
            *(float4*)(&xs[r][c4]) = v;
        }
    }
    __syncthreads();

    // phase 1: hidden = relu(h1 @ W1 + bb1); cols {tx*4, 64+tx*4}
    {
        const int r0 = ty * 2, r1 = r0 + 1;
        const int cA = tx * 4, cB = 64 + tx * 4;
        float4 aA0 = make_float4(0,0,0,0), aA1 = aA0, aB0 = aA0, aB1 = aA0;
        #pragma unroll 4
        for (int c = 0; c < 64; ++c) {
            const float4 wA = *(const float4*)(W1 + c * 128 + cA);
            const float4 wB = *(const float4*)(W1 + c * 128 + cB);
            const float x0 = xs[r0][c];
            const float x1 = xs[r1][c];
            aA0.x = fmaf(x0, wA.x, aA0.x); aA0.y = fmaf(x0, wA.y, aA0.y);
            aA0.z = fmaf(x0, wA.z, aA0.z); aA0.w = fmaf(x0, wA.w, aA0.w);
            aA1.x = fmaf(x1, wA.x, aA1.x); aA1.y = fmaf(x1, wA.y, aA1.y);
            aA1.z = fmaf(x1, wA.z, aA1.z); aA1.w = fmaf(x1, wA.w, aA1.w);
            aB0.x = fmaf(x0, wB.x, aB0.x); aB0.y = fmaf(x0, wB.y, aB0.y);
            aB0.z = fmaf(x0, wB.z, aB0.z); aB0.w = fmaf(x0, wB.w, aB0.w);
            aB1.x = fmaf(x1, wB.x, aB1.x); aB1.y = fmaf(x1, wB.y, aB1.y);
            aB1.z = fmaf(x1, wB.z, aB1.z); aB1.w = fmaf(x1, wB.w, aB1.w);
        }
        const float4 b1A = *(const float4*)(bb1 + cA);
        const float4 b1B = *(const float4*)(bb1 + cB);
        aA0.x = fmaxf(aA0.x + b1A.x, 0.f); aA0.y = fmaxf(aA0.y + b1A.y, 0.f);
        aA0.z = fmaxf(aA0.z + b1A.z, 0.f); aA0.w = fmaxf(aA0.w + b1A.w, 0.f);
        aA1.x = fmaxf(aA1.x + b1A.x, 0.f); aA1.y = fmaxf(aA1.y + b1A.y, 0.f);
        aA1.z = fmaxf(aA1.z + b1A.z, 0.f); aA1.w = fmaxf(aA1.w + b1A.w, 0.f);
        aB0.x = fmaxf(aB0.x + b1B.x, 0.f); aB0.y = fmaxf(aB0.y + b1B.y, 0.f);
        aB0.z = fmaxf(aB0.z + b1B.z, 0.f); aB0.w = fmaxf(aB0.w + b1B.w, 0.f);
        aB1.x = fmaxf(aB1.x + b1B.x, 0.f); aB1.y = fmaxf(aB1.y + b1B.y, 0.f);
        aB1.z = fmaxf(aB1.z + b1B.z, 0.f); aB1.w = fmaxf(aB1.w + b1B.w, 0.f);
        *(float4*)(&ts[r0][cA]) = aA0;
        *(float4*)(&ts[r1][cA]) = aA1;
        *(float4*)(&ts[r0][cB]) = aB0;
        *(float4*)(&ts[r1][cB]) = aB1;
    }
    __syncthreads();

    // phase 2: y = h1 + T @ W2 + bb2; thread: rows {ty*2, ty*2+1}, cols tx*4
    {
        const int r0 = ty * 2, r1 = r0 + 1;
        const int c4 = tx * 4;
        float4 y0 = make_float4(0,0,0,0), y1 = y0;
        #pragma unroll 4
        for (int k = 0; k < 128; ++k) {
            const float4 w = *(const float4*)(W2 + k * 64 + c4);
            const float T0 = ts[r0][k];
            const float T1 = ts[r1][k];
            y0.x = fmaf(T0, w.x, y0.x); y0.y = fmaf(T0, w.y, y0.y);
            y0.z = fmaf(T0, w.z, y0.z); y0.w = fmaf(T0, w.w, y0.w);
            y1.x = fmaf(T1, w.x, y1.x); y1.y = fmaf(T1, w.y, y1.y);
            y1.z = fmaf(T1, w.z, y1.z); y1.w = fmaf(T1, w.w, y1.w);
        }
        const float4 bb = *(const float4*)(bb2 + c4);
        const float4 h0 = *(const float4*)(&xs[r0][c4]);
        const float4 h1v = *(const float4*)(&xs[r1][c4]);
        y0.x += bb.x + h0.x;  y0.y += bb.y + h0.y;
        y0.z += bb.z + h0.z;  y0.w += bb.w + h0.w;
        y1.x += bb.x + h1v.x; y1.y += bb.y + h1v.y;
        y1.z += bb.z + h1v.z; y1.w += bb.w + h1v.w;

        const bool v0 = (row0 + r0) < N_NODES;
        const bool v1 = (row0 + r1) < N_NODES;
        if (v0) *(float4*)(y + (size_t)(row0 + r0) * 64 + c4) = y0;
        if (v1) *(float4*)(y + (size_t)(row0 + r1) * 64 + c4) = y1;

        float4 s = make_float4(0,0,0,0), q = s;
        if (v0) {
            s.x += y0.x; s.y += y0.y; s.z += y0.z; s.w += y0.w;
            q.x += y0.x*y0.x; q.y += y0.y*y0.y; q.z += y0.z*y0.z; q.w += y0.w*y0.w;
        }
        if (v1) {
            s.x += y1.x; s.y += y1.y; s.z += y1.z; s.w += y1.w;
            q.x += y1.x*y1.x; q.y += y1.y*y1.y; q.z += y1.z*y1.z; q.w += y1.w*y1.w;
        }
        *(float4*)(&reds[ty][c4]) = s;
        *(float4*)(&redq[ty][c4]) = q;
    }
    __syncthreads();
    if (t < 64) {
        float s = 0.f, q = 0.f;
        #pragma unroll
        for (int k = 0; k < 16; ++k) { s += reds[k][t]; q += redq[k][t]; }
        atomicAdd(s2 + t, s);
        atomicAdd(sq2 + t, q);
    }
}

// ---------------------------------------------------------------------------
// K6: apply BN2 in place on y, float4.
// ---------------------------------------------------------------------------
__global__ __launch_bounds__(256) void bn2_apply_kernel(
    float* __restrict__ y,
    const float* __restrict__ m2, const float* __restrict__ rs2,
    const float* __restrict__ g2, const float* __restrict__ b2)
{
    const int total4 = N_NODES * 16;   // float4 count
    const int stride = gridDim.x * blockDim.x;
    for (int i = blockIdx.x * blockDim.x + threadIdx.x; i < total4; i += stride) {
        const int c4 = (i & 15) * 4;
        const float4 mm = *(const float4*)(m2 + c4);
        const float4 rr = *(const float4*)(rs2 + c4);
        const float4 gg = *(const float4*)(g2 + c4);
        const float4 bb = *(const float4*)(b2 + c4);
        float4 v = *((float4*)y + i);
        v.x = (v.x - mm.x) * rr.x * gg.x + bb.x;
        v.y = (v.y - mm.y) * rr.y * gg.y + bb.y;
        v.z = (v.z - mm.z) * rr.z * gg.z + bb.z;
        v.w = (v.w - mm.w) * rr.w * gg.w + bb.w;
        *((float4*)y + i) = v;
    }
}

extern "C" void kernel_launch(void* const* d_in, const int* in_sizes, int n_in,
                              void* d_out, int out_size, void* d_ws, size_t ws_size,
                              hipStream_t stream)
{
    const float* h   = (const float*)d_in[0];
    const int*   src = (const int*)d_in[1];
    const int*   dst = (const int*)d_in[2];
    const float* Wq  = (const float*)d_in[3];
    const float* bq  = (const float*)d_in[4];
    const float* Wk  = (const float*)d_in[5];
    const float* bk  = (const float*)d_in[6];
    const float* Wv  = (const float*)d_in[7];
    const float* bv  = (const float*)d_in[8];
    const float* g1  = (const float*)d_in[9];
    const float* b1  = (const float*)d_in[10];
    const float* W1  = (const float*)d_in[11];
    const float* bb1 = (const float*)d_in[12];
    const float* W2  = (const float*)d_in[13];
    const float* bb2 = (const float*)d_in[14];
    const float* g2  = (const float*)d_in[15];
    const float* b2  = (const float*)d_in[16];
    float* out = (float*)d_out;

    float* ws = (float*)d_ws;
    const size_t ND = (size_t)N_NODES * 64;
    float* Q = ws;            // reused as x (safe: Q[n] read before x[n] write)
    float* K = ws + ND;
    float* V = ws + 2 * ND;
    float* x = Q;
    int* srcSorted = (int*)(ws + 3 * ND);          // E
    int* count     = srcSorted + E_EDGES;          // N   (zeroed)
    float* st      = (float*)(count + N_NODES);    // 512 floats (zeroed)
    int* rowStart  = (int*)(st + 512);             // N+1
    int* cursor    = rowStart + N_NODES + 1;       // N
    float* s1 = st,       *sq1 = st + 64,  *m1 = st + 128, *rs1 = st + 192;
    float* s2 = st + 256, *sq2 = st + 320, *m2 = st + 384, *rs2 = st + 448;

    hipMemsetAsync(count, 0, (N_NODES + 512) * sizeof(int), stream);

    qkv_kernel<<<(N_NODES + 63) / 64, 256, 0, stream>>>(
        h, Wq, bq, Wk, bk, Wv, bv, Q, K, V);
    hist_kernel<<<3125, 256, 0, stream>>>(dst, count);
    scan_kernel<<<1, 1024, 0, stream>>>(count, rowStart, cursor);
    scatter_kernel<<<3125, 256, 0, stream>>>(src, dst, cursor, srcSorted);
    gather_edge_kernel<<<1024, 256, 0, stream>>>(h, Q, K, V, rowStart, srcSorted,
                                                 x, s1, sq1);
    stats_fin_kernel<<<1, 64, 0, stream>>>(s1, sq1, m1, rs1);
    ffn_kernel<<<(N_NODES + 31) / 32, 256, 0, stream>>>(
        x, m1, rs1, g1, b1, W1, bb1, W2, bb2, out, s2, sq2);
    stats_fin_kernel<<<1, 64, 0, stream>>>(s2, sq2, m2, rs2);
    bn2_apply_kernel<<<2048, 256, 0, stream>>>(out, m2, rs2, g2, b2);
}

// Round 4
// 404.355 us; speedup vs baseline: 5.0319x; 1.2395x over previous
//
#include <hip/hip_runtime.h>
#include <math.h>

#define N_NODES 50000
#define E_EDGES 800000
#define EPS_BN  1e-5f
#define SCAN_BLOCKS 196   // ceil(N_NODES/256)

// ---------------------------------------------------------------------------
// K1: fused QKV GEMM, register-tiled. Block = 256 thr, tile = 64 rows.
// ---------------------------------------------------------------------------
__global__ __launch_bounds__(256) void qkv_kernel(
    const float* __restrict__ h,
    const float* __restrict__ Wq, const float* __restrict__ bq,
    const float* __restrict__ Wk, const float* __restrict__ bk,
    const float* __restrict__ Wv, const float* __restrict__ bv,
    float* __restrict__ Q, float* __restrict__ K, float* __restrict__ V)
{
    __shared__ float xs[64][68];
    const int t  = threadIdx.x;
    const int tx = t & 15;
    const int ty = t >> 4;
    const int row0 = blockIdx.x * 64;

    #pragma unroll
    for (int k = 0; k < 4; ++k) {
        const int i  = t + k * 256;
        const int r  = i >> 4;
        const int c4 = (i & 15) * 4;
        float4 v = make_float4(0.f, 0.f, 0.f, 0.f);
        if (row0 + r < N_NODES)
            v = *(const float4*)(h + (size_t)(row0 + r) * 64 + c4);
        *(float4*)(&xs[r][c4]) = v;
    }
    __syncthreads();

    const int c0 = tx * 4;
    float4 aq[4], ak[4], av[4];
    const float4 bq4 = *(const float4*)(bq + c0);
    const float4 bk4 = *(const float4*)(bk + c0);
    const float4 bv4 = *(const float4*)(bv + c0);
    #pragma unroll
    for (int i = 0; i < 4; ++i) { aq[i] = bq4; ak[i] = bk4; av[i] = bv4; }

    #pragma unroll 4
    for (int c = 0; c < 64; ++c) {
        const float4 wq = *(const float4*)(Wq + c * 64 + c0);
        const float4 wk = *(const float4*)(Wk + c * 64 + c0);
        const float4 wv = *(const float4*)(Wv + c * 64 + c0);
        #pragma unroll
        for (int i = 0; i < 4; ++i) {
            const float xv = xs[ty * 4 + i][c];
            aq[i].x = fmaf(xv, wq.x, aq[i].x); aq[i].y = fmaf(xv, wq.y, aq[i].y);
            aq[i].z = fmaf(xv, wq.z, aq[i].z); aq[i].w = fmaf(xv, wq.w, aq[i].w);
            ak[i].x = fmaf(xv, wk.x, ak[i].x); ak[i].y = fmaf(xv, wk.y, ak[i].y);
            ak[i].z = fmaf(xv, wk.z, ak[i].z); ak[i].w = fmaf(xv, wk.w, ak[i].w);
            av[i].x = fmaf(xv, wv.x, av[i].x); av[i].y = fmaf(xv, wv.y, av[i].y);
            av[i].z = fmaf(xv, wv.z, av[i].z); av[i].w = fmaf(xv, wv.w, av[i].w);
        }
    }
    #pragma unroll
    for (int i = 0; i < 4; ++i) {
        const int row = row0 + ty * 4 + i;
        if (row < N_NODES) {
            *(float4*)(Q + (size_t)row * 64 + c0) = aq[i];
            *(float4*)(K + (size_t)row * 64 + c0) = ak[i];
            *(float4*)(V + (size_t)row * 64 + c0) = av[i];
        }
    }
}

// ---------------------------------------------------------------------------
// K2a: histogram of dst.
// ---------------------------------------------------------------------------
__global__ __launch_bounds__(256) void hist_kernel(
    const int* __restrict__ dst, int* __restrict__ count)
{
    const int e = blockIdx.x * 256 + threadIdx.x;
    if (e < E_EDGES) atomicAdd(&count[dst[e]], 1);
}

// ---------------------------------------------------------------------------
// K2b-1: per-block scan. Each block scans 256 counts; writes block-local
// exclusive prefix into rowStart and its total into blockSums.
// ---------------------------------------------------------------------------
__global__ __launch_bounds__(256) void scanA_kernel(
    const int* __restrict__ count,
    int* __restrict__ rowStart, int* __restrict__ blockSums)
{
    __shared__ int ls[256];
    const int t = threadIdx.x;
    const int i = blockIdx.x * 256 + t;
    const int v = (i < N_NODES) ? count[i] : 0;
    ls[t] = v;
    __syncthreads();
    #pragma unroll
    for (int off = 1; off < 256; off <<= 1) {
        const int u = (t >= off) ? ls[t - off] : 0;
        __syncthreads();
        ls[t] += u;
        __syncthreads();
    }
    if (i < N_NODES) rowStart[i] = ls[t] - v;      // exclusive, block-local
    if (t == 255) blockSums[blockIdx.x] = ls[255];
}

// ---------------------------------------------------------------------------
// K2b-2: scan the block sums (196 entries) -> exclusive offsets.
// ---------------------------------------------------------------------------
__global__ __launch_bounds__(256) void scanB_kernel(int* __restrict__ blockSums)
{
    __shared__ int ls[256];
    const int t = threadIdx.x;
    const int v = (t < SCAN_BLOCKS) ? blockSums[t] : 0;
    ls[t] = v;
    __syncthreads();
    #pragma unroll
    for (int off = 1; off < 256; off <<= 1) {
        const int u = (t >= off) ? ls[t - off] : 0;
        __syncthreads();
        ls[t] += u;
        __syncthreads();
    }
    if (t < SCAN_BLOCKS) blockSums[t] = ls[t] - v; // exclusive
}

// ---------------------------------------------------------------------------
// K2b-3: add block offsets; emit rowStart + cursor; rowStart[N]=E.
// ---------------------------------------------------------------------------
__global__ __launch_bounds__(256) void scanC_kernel(
    int* __restrict__ rowStart, int* __restrict__ cursor,
    const int* __restrict__ blockSums)
{
    const int i = blockIdx.x * 256 + threadIdx.x;
    if (i < N_NODES) {
        const int v = rowStart[i] + blockSums[blockIdx.x];
        rowStart[i] = v;
        cursor[i]   = v;
    }
    if (i == 0) rowStart[N_NODES] = E_EDGES;
}

// ---------------------------------------------------------------------------
// K2c: scatter src into dst-sorted order.
// ---------------------------------------------------------------------------
__global__ __launch_bounds__(256) void scatter_kernel(
    const int* __restrict__ src, const int* __restrict__ dst,
    int* __restrict__ cursor, int* __restrict__ srcSorted)
{
    const int e = blockIdx.x * 256 + threadIdx.x;
    if (e < E_EDGES) {
        const int pos = atomicAdd(&cursor[dst[e]], 1);
        srcSorted[pos] = src[e];
    }
}

// ---------------------------------------------------------------------------
// K3: gather edge aggregation + attn-normalize + residual + BN1 partials.
// One wave per dst node; lane&7 = head, lane>>3 = edge slot.
// ---------------------------------------------------------------------------
__global__ __launch_bounds__(256) void gather_edge_kernel(
    const float* __restrict__ h,
    const float* __restrict__ Q, const float* __restrict__ K,
    const float* __restrict__ V,
    const int* __restrict__ rowStart, const int* __restrict__ srcSorted,
    float* __restrict__ x, float* __restrict__ s1, float* __restrict__ sq1)
{
    const int lane = threadIdx.x & 63;
    const int wave = threadIdx.x >> 6;
    const int hh = lane & 7;
    const int el = lane >> 3;
    float bsum[8], bsq[8];
    #pragma unroll
    for (int j = 0; j < 8; ++j) { bsum[j] = 0.0f; bsq[j] = 0.0f; }

    const int nodeStep = gridDim.x * 4;
    for (int n = blockIdx.x * 4 + wave; n < N_NODES; n += nodeStep) {
        const int start = rowStart[n];
        const int end   = rowStart[n + 1];
        const size_t qb = (size_t)n * 64 + hh * 8;
        const float4 q0 = *(const float4*)(Q + qb);
        const float4 q1 = *(const float4*)(Q + qb + 4);
        float a0=0,a1=0,a2=0,a3=0,a4=0,a5=0,a6=0,a7=0,zacc=0;
        for (int e = start + el; e < end; e += 8) {
            const int s = srcSorted[e];
            const size_t kb = (size_t)s * 64 + hh * 8;
            const float4 k0 = *(const float4*)(K + kb);
            const float4 k1 = *(const float4*)(K + kb + 4);
            float sc = k0.x*q0.x + k0.y*q0.y + k0.z*q0.z + k0.w*q0.w
                     + k1.x*q1.x + k1.y*q1.y + k1.z*q1.z + k1.w*q1.w;
            sc *= 0.35355339059327373f;
            sc = fminf(5.0f, fmaxf(-5.0f, sc));
            const float p = __expf(sc);
            const float4 v0 = *(const float4*)(V + kb);
            const float4 v1 = *(const float4*)(V + kb + 4);
            a0 = fmaf(p, v0.x, a0); a1 = fmaf(p, v0.y, a1);
            a2 = fmaf(p, v0.z, a2); a3 = fmaf(p, v0.w, a3);
            a4 = fmaf(p, v1.x, a4); a5 = fmaf(p, v1.y, a5);
            a6 = fmaf(p, v1.z, a6); a7 = fmaf(p, v1.w, a7);
            zacc += p;
        }
        #pragma unroll
        for (int m = 8; m < 64; m <<= 1) {
            a0 += __shfl_xor(a0, m, 64); a1 += __shfl_xor(a1, m, 64);
            a2 += __shfl_xor(a2, m, 64); a3 += __shfl_xor(a3, m, 64);
            a4 += __shfl_xor(a4, m, 64); a5 += __shfl_xor(a5, m, 64);
            a6 += __shfl_xor(a6, m, 64); a7 += __shfl_xor(a7, m, 64);
            zacc += __shfl_xor(zacc, m, 64);
        }
        if (el == 0) {
            const float inv = (zacc == 0.0f) ? 0.0f : 1.0f / zacc;
            const float4 h0 = *(const float4*)(h + qb);
            const float4 h1 = *(const float4*)(h + qb + 4);
            float xv[8];
            xv[0] = fmaf(a0, inv, h0.x); xv[1] = fmaf(a1, inv, h0.y);
            xv[2] = fmaf(a2, inv, h0.z); xv[3] = fmaf(a3, inv, h0.w);
            xv[4] = fmaf(a4, inv, h1.x); xv[5] = fmaf(a5, inv, h1.y);
            xv[6] = fmaf(a6, inv, h1.z); xv[7] = fmaf(a7, inv, h1.w);
            *(float4*)(x + qb)     = make_float4(xv[0], xv[1], xv[2], xv[3]);
            *(float4*)(x + qb + 4) = make_float4(xv[4], xv[5], xv[6], xv[7]);
            #pragma unroll
            for (int j = 0; j < 8; ++j) {
                bsum[j] += xv[j];
                bsq[j]  += xv[j] * xv[j];
            }
        }
    }
    __shared__ float lsm[256];
    __shared__ float lsq[256];
    if (el == 0) {
        #pragma unroll
        for (int j = 0; j < 8; ++j) {
            lsm[wave * 64 + hh * 8 + j] = bsum[j];
            lsq[wave * 64 + hh * 8 + j] = bsq[j];
        }
    }
    __syncthreads();
    if (threadIdx.x < 64) {
        const int tt = threadIdx.x;
        const float s = lsm[tt] + lsm[tt + 64] + lsm[tt + 128] + lsm[tt + 192];
        const float q = lsq[tt] + lsq[tt + 64] + lsq[tt + 128] + lsq[tt + 192];
        atomicAdd(s1 + tt, s);
        atomicAdd(sq1 + tt, q);
    }
}

// ---------------------------------------------------------------------------
// K4: finalize BN stats.
// ---------------------------------------------------------------------------
__global__ void stats_fin_kernel(const float* __restrict__ s,
                                 const float* __restrict__ sq,
                                 float* __restrict__ m, float* __restrict__ rs)
{
    const int c = threadIdx.x;
    const float mean = s[c] * (1.0f / N_NODES);
    const float var  = sq[c] * (1.0f / N_NODES) - mean * mean;
    m[c]  = mean;
    rs[c] = rsqrtf(var + EPS_BN);
}

// ---------------------------------------------------------------------------
// K5: fused BN1-apply + FFN + residual + BN2 partials, register-tiled.
// ---------------------------------------------------------------------------
__global__ __launch_bounds__(256) void ffn_kernel(
    const float* __restrict__ x,
    const float* __restrict__ m1, const float* __restrict__ rs1,
    const float* __restrict__ g1, const float* __restrict__ b1,
    const float* __restrict__ W1, const float* __restrict__ bb1,
    const float* __restrict__ W2, const float* __restrict__ bb2,
    float* __restrict__ y, float* __restrict__ s2, float* __restrict__ sq2)
{
    __shared__ float xs[32][68];
    __shared__ float ts[32][132];
    __shared__ float reds[16][64];
    __shared__ float redq[16][64];

    const int t  = threadIdx.x;
    const int tx = t & 15;
    const int ty = t >> 4;
    const int row0 = blockIdx.x * 32;

    {
        const int c4 = (t & 15) * 4;
        const float4 mm = *(const float4*)(m1 + c4);
        const float4 rr = *(const float4*)(rs1 + c4);
        const float4 gg = *(const float4*)(g1 + c4);
        const float4 bb = *(const float4*)(b1 + c4);
        float4 A, C;
        A.x = rr.x * gg.x; C.x = bb.x - mm.x * A.x;
        A.y = rr.y * gg.y; C.y = bb.y - mm.y * A.y;
        A.z = rr.z * gg.z; C.z = bb.z - mm.z * A.z;
        A.w = rr.w * gg.w; C.w = bb.w - mm.w * A.w;
        #pragma unroll
        for (int k = 0; k < 2; ++k) {
            const int i = t + k * 256;
            const int r = i >> 4;
            float4 v = make_float4(0.f, 0.f, 0.f, 0.f);
            if (row0 + r < N_NODES) {
                const float4 xv = *(const float4*)(x + (size_t)(row0 + r) * 64 + c4);
                v.x = fmaf(xv.x, A.x, C.x);
                v.y = fmaf(xv.y, A.y, C.y);
                v.z = fmaf(xv.z, A.z, C.z);
                v.w = fmaf(xv.w, A.w, C.w);
            }
            *(float4*)(&xs[r][c4]) = v;
        }
    }
    __syncthreads();

    {
        const int r0 = ty * 2, r1 = r0 + 1;
        const int cA = tx * 4, cB = 64 + tx * 4;
        float4 aA0 = make_float4(0,0,0,0), aA1 = aA0, aB0 = aA0, aB1 = aA0;
        #pragma unroll 4
        for (int c = 0; c < 64; ++c) {
            const float4 wA = *(const float4*)(W1 + c * 128 + cA);
            const float4 wB = *(const float4*)(W1 + c * 128 + cB);
            const float x0 = xs[r0][c];
            const float x1 = xs[r1][c];
            aA0.x = fmaf(x0, wA.x, aA0.x); aA0.y = fmaf(x0, wA.y, aA0.y);
            aA0.z = fmaf(x0, wA.z, aA0.z); aA0.w = fmaf(x0, wA.w, aA0.w);
            aA1.x = fmaf(x1, wA.x, aA1.x); aA1.y = fmaf(x1, wA.y, aA1.y);
            aA1.z = fmaf(x1, wA.z, aA1.z); aA1.w = fmaf(x1, wA.w, aA1.w);
            aB0.x = fmaf(x0, wB.x, aB0.x); aB0.y = fmaf(x0, wB.y, aB0.y);
            aB0.z = fmaf(x0, wB.z, aB0.z); aB0.w = fmaf(x0, wB.w, aB0.w);
            aB1.x = fmaf(x1, wB.x, aB1.x); aB1.y = fmaf(x1, wB.y, aB1.y);
            aB1.z = fmaf(x1, wB.z, aB1.z); aB1.w = fmaf(x1, wB.w, aB1.w);
        }
        const float4 b1A = *(const float4*)(bb1 + cA);
        const float4 b1B = *(const float4*)(bb1 + cB);
        aA0.x = fmaxf(aA0.x + b1A.x, 0.f); aA0.y = fmaxf(aA0.y + b1A.y, 0.f);
        aA0.z = fmaxf(aA0.z + b1A.z, 0.f); aA0.w = fmaxf(aA0.w + b1A.w, 0.f);
        aA1.x = fmaxf(aA1.x + b1A.x, 0.f); aA1.y = fmaxf(aA1.y + b1A.y, 0.f);
        aA1.z = fmaxf(aA1.z + b1A.z, 0.f); aA1.w = fmaxf(aA1.w + b1A.w, 0.f);
        aB0.x = fmaxf(aB0.x + b1B.x, 0.f); aB0.y = fmaxf(aB0.y + b1B.y, 0.f);
        aB0.z = fmaxf(aB0.z + b1B.z, 0.f); aB0.w = fmaxf(aB0.w + b1B.w, 0.f);
        aB1.x = fmaxf(aB1.x + b1B.x, 0.f); aB1.y = fmaxf(aB1.y + b1B.y, 0.f);
        aB1.z = fmaxf(aB1.z + b1B.z, 0.f); aB1.w = fmaxf(aB1.w + b1B.w, 0.f);
        *(float4*)(&ts[r0][cA]) = aA0;
        *(float4*)(&ts[r1][cA]) = aA1;
        *(float4*)(&ts[r0][cB]) = aB0;
        *(float4*)(&ts[r1][cB]) = aB1;
    }
    __syncthreads();

    {
        const int r0 = ty * 2, r1 = r0 + 1;
        const int c4 = tx * 4;
        float4 y0 = make_float4(0,0,0,0), y1 = y0;
        #pragma unroll 4
        for (int k = 0; k < 128; ++k) {
            const float4 w = *(const float4*)(W2 + k * 64 + c4);
            const float T0 = ts[r0][k];
            const float T1 = ts[r1][k];
            y0.x = fmaf(T0, w.x, y0.x); y0.y = fmaf(T0, w.y, y0.y);
            y0.z = fmaf(T0, w.z, y0.z); y0.w = fmaf(T0, w.w, y0.w);
            y1.x = fmaf(T1, w.x, y1.x); y1.y = fmaf(T1, w.y, y1.y);
            y1.z = fmaf(T1, w.z, y1.z); y1.w = fmaf(T1, w.w, y1.w);
        }
        const float4 bb = *(const float4*)(bb2 + c4);
        const float4 h0 = *(const float4*)(&xs[r0][c4]);
        const float4 h1v = *(const float4*)(&xs[r1][c4]);
        y0.x += bb.x + h0.x;  y0.y += bb.y + h0.y;
        y0.z += bb.z + h0.z;  y0.w += bb.w + h0.w;
        y1.x += bb.x + h1v.x; y1.y += bb.y + h1v.y;
        y1.z += bb.z + h1v.z; y1.w += bb.w + h1v.w;

        const bool v0 = (row0 + r0) < N_NODES;
        const bool v1 = (row0 + r1) < N_NODES;
        if (v0) *(float4*)(y + (size_t)(row0 + r0) * 64 + c4) = y0;
        if (v1) *(float4*)(y + (size_t)(row0 + r1) * 64 + c4) = y1;

        float4 s = make_float4(0,0,0,0), q = s;
        if (v0) {
            s.x += y0.x; s.y += y0.y; s.z += y0.z; s.w += y0.w;
            q.x += y0.x*y0.x; q.y += y0.y*y0.y; q.z += y0.z*y0.z; q.w += y0.w*y0.w;
        }
        if (v1) {
            s.x += y1.x; s.y += y1.y; s.z += y1.z; s.w += y1.w;
            q.x += y1.x*y1.x; q.y += y1.y*y1.y; q.z += y1.z*y1.z; q.w += y1.w*y1.w;
        }
        *(float4*)(&reds[ty][c4]) = s;
        *(float4*)(&redq[ty][c4]) = q;
    }
    __syncthreads();
    if (t < 64) {
        float s = 0.f, q = 0.f;
        #pragma unroll
        for (int k = 0; k < 16; ++k) { s += reds[k][t]; q += redq[k][t]; }
        atomicAdd(s2 + t, s);
        atomicAdd(sq2 + t, q);
    }
}

// ---------------------------------------------------------------------------
// K6: apply BN2 in place on y, float4.
// ---------------------------------------------------------------------------
__global__ __launch_bounds__(256) void bn2_apply_kernel(
    float* __restrict__ y,
    const float* __restrict__ m2, const float* __restrict__ rs2,
    const float* __restrict__ g2, const float* __restrict__ b2)
{
    const int total4 = N_NODES * 16;
    const int stride = gridDim.x * blockDim.x;
    for (int i = blockIdx.x * blockDim.x + threadIdx.x; i < total4; i += stride) {
        const int c4 = (i & 15) * 4;
        const float4 mm = *(const float4*)(m2 + c4);
        const float4 rr = *(const float4*)(rs2 + c4);
        const float4 gg = *(const float4*)(g2 + c4);
        const float4 bb = *(const float4*)(b2 + c4);
        float4 v = *((float4*)y + i);
        v.x = (v.x - mm.x) * rr.x * gg.x + bb.x;
        v.y = (v.y - mm.y) * rr.y * gg.y + bb.y;
        v.z = (v.z - mm.z) * rr.z * gg.z + bb.z;
        v.w = (v.w - mm.w) * rr.w * gg.w + bb.w;
        *((float4*)y + i) = v;
    }
}

extern "C" void kernel_launch(void* const* d_in, const int* in_sizes, int n_in,
                              void* d_out, int out_size, void* d_ws, size_t ws_size,
                              hipStream_t stream)
{
    const float* h   = (const float*)d_in[0];
    const int*   src = (const int*)d_in[1];
    const int*   dst = (const int*)d_in[2];
    const float* Wq  = (const float*)d_in[3];
    const float* bq  = (const float*)d_in[4];
    const float* Wk  = (const float*)d_in[5];
    const float* bk  = (const float*)d_in[6];
    const float* Wv  = (const float*)d_in[7];
    const float* bv  = (const float*)d_in[8];
    const float* g1  = (const float*)d_in[9];
    const float* b1  = (const float*)d_in[10];
    const float* W1  = (const float*)d_in[11];
    const float* bb1 = (const float*)d_in[12];
    const float* W2  = (const float*)d_in[13];
    const float* bb2 = (const float*)d_in[14];
    const float* g2  = (const float*)d_in[15];
    const float* b2  = (const float*)d_in[16];
    float* out = (float*)d_out;

    float* ws = (float*)d_ws;
    const size_t ND = (size_t)N_NODES * 64;
    float* Q = ws;            // reused as x (safe: Q[n] read before x[n] write)
    float* K = ws + ND;
    float* V = ws + 2 * ND;
    float* x = Q;
    int* srcSorted = (int*)(ws + 3 * ND);          // E
    int* count     = srcSorted + E_EDGES;          // N   (zeroed)
    float* st      = (float*)(count + N_NODES);    // 512 floats (zeroed)
    int* rowStart  = (int*)(st + 512);             // N+1
    int* cursor    = rowStart + N_NODES + 1;       // N
    int* blockSums = cursor + N_NODES;             // SCAN_BLOCKS
    float* s1 = st,       *sq1 = st + 64,  *m1 = st + 128, *rs1 = st + 192;
    float* s2 = st + 256, *sq2 = st + 320, *m2 = st + 384, *rs2 = st + 448;

    hipMemsetAsync(count, 0, (N_NODES + 512) * sizeof(int), stream);

    qkv_kernel<<<(N_NODES + 63) / 64, 256, 0, stream>>>(
        h, Wq, bq, Wk, bk, Wv, bv, Q, K, V);
    hist_kernel<<<3125, 256, 0, stream>>>(dst, count);
    scanA_kernel<<<SCAN_BLOCKS, 256, 0, stream>>>(count, rowStart, blockSums);
    scanB_kernel<<<1, 256, 0, stream>>>(blockSums);
    scanC_kernel<<<SCAN_BLOCKS, 256, 0, stream>>>(rowStart, cursor, blockSums);
    scatter_kernel<<<3125, 256, 0, stream>>>(src, dst, cursor, srcSorted);
    gather_edge_kernel<<<1024, 256, 0, stream>>>(h, Q, K, V, rowStart, srcSorted,
                                                 x, s1, sq1);
    stats_fin_kernel<<<1, 64, 0, stream>>>(s1, sq1, m1, rs1);
    ffn_kernel<<<(N_NODES + 31) / 32, 256, 0, stream>>>(
        x, m1, rs1, g1, b1, W1, bb1, W2, bb2, out, s2, sq2);
    stats_fin_kernel<<<1, 64, 0, stream>>>(s2, sq2, m2, rs2);
    bn2_apply_kernel<<<2048, 256, 0, stream>>>(out, m2, rs2, g2, b2);
}